// Round 1
// baseline (894.114 us; speedup 1.0000x reference)
//
#include <hip/hip_runtime.h>

#define NB 256
#define NT 1024
#define NH 512
#define NI 3
#define NO 3

// DPP-based wave64 reduction: after the ladder, lane 63 holds the full sum.
template<int CTRL>
__device__ __forceinline__ float dpp_add(float x) {
  int y = __builtin_amdgcn_update_dpp(0, __float_as_int(x), CTRL, 0xf, 0xf, false);
  return x + __int_as_float(y);
}

__device__ __forceinline__ float wave_sum63(float x) {
  x = dpp_add<0x111>(x);  // row_shr:1
  x = dpp_add<0x112>(x);  // row_shr:2
  x = dpp_add<0x114>(x);  // row_shr:4
  x = dpp_add<0x118>(x);  // row_shr:8
  x = dpp_add<0x142>(x);  // row_bcast:15
  x = dpp_add<0x143>(x);  // row_bcast:31
  return x;               // lane 63 = total
}

__device__ __forceinline__ float bcast_lane63(float x) {
  return __int_as_float(__builtin_amdgcn_readlane(__float_as_int(x), 63));
}

__device__ __forceinline__ float fast_tanh(float x) {
  // tanh(x) = 1 - 2/(exp(2x)+1); exp(2x) = exp2(x * 2*log2(e))
  float e = __builtin_amdgcn_exp2f(x * 2.885390081777927f);
  float r = __builtin_amdgcn_rcpf(e + 1.0f);
  return fmaf(-2.0f, r, 1.0f);
}

__global__ __launch_bounds__(64, 1)
void lowrank_rnn_kernel(const float* __restrict__ x,
                        const float* __restrict__ hidden,
                        const float* __restrict__ U,
                        const float* __restrict__ V,
                        const float* __restrict__ W_in,
                        const float* __restrict__ b_in,
                        const float* __restrict__ W_out,
                        const float* __restrict__ b_out,
                        float* __restrict__ out_y,   // [B,T,NO]
                        float* __restrict__ out_h,   // [B,NH]
                        float* __restrict__ out_r) { // [B,T,NH]
  const int b = blockIdx.x;
  const int lane = threadIdx.x;  // 0..63

  __shared__ float xs[NT * NI];  // 12 KB: x for this batch element

  // ---- stage x[b] into LDS (coalesced float4) ----
  {
    const float4* src = (const float4*)(x + (size_t)b * NT * NI);
    float4* dst = (float4*)xs;
#pragma unroll
    for (int i = 0; i < (NT * NI / 4) / 64; ++i)  // 12 iters
      dst[i * 64 + lane] = src[i * 64 + lane];
  }

  // Lane j-slot -> hidden index: j<4 : h = 4*lane+j ; j>=4 : h = 256+4*lane+(j-4)
  // ---- preload weights into registers ----
  float Uv[4][8], Vv[4][8];
#pragma unroll
  for (int r = 0; r < 4; ++r) {
    float4 u0 = ((const float4*)U)[r * 128 + lane];
    float4 u1 = ((const float4*)U)[r * 128 + 64 + lane];
    Uv[r][0] = u0.x; Uv[r][1] = u0.y; Uv[r][2] = u0.z; Uv[r][3] = u0.w;
    Uv[r][4] = u1.x; Uv[r][5] = u1.y; Uv[r][6] = u1.z; Uv[r][7] = u1.w;
    float4 v0 = ((const float4*)V)[r * 128 + lane];
    float4 v1 = ((const float4*)V)[r * 128 + 64 + lane];
    Vv[r][0] = v0.x; Vv[r][1] = v0.y; Vv[r][2] = v0.z; Vv[r][3] = v0.w;
    Vv[r][4] = v1.x; Vv[r][5] = v1.y; Vv[r][6] = v1.z; Vv[r][7] = v1.w;
  }

  float Wi[8][3];
#pragma unroll
  for (int j = 0; j < 8; ++j) {
    int h = (j < 4) ? (4 * lane + j) : (256 + 4 * lane + (j - 4));
    Wi[j][0] = W_in[h * 3 + 0];
    Wi[j][1] = W_in[h * 3 + 1];
    Wi[j][2] = W_in[h * 3 + 2];
  }

  float bin[8];
  {
    float4 b0 = ((const float4*)b_in)[lane];
    float4 b1 = ((const float4*)b_in)[64 + lane];
    bin[0] = b0.x; bin[1] = b0.y; bin[2] = b0.z; bin[3] = b0.w;
    bin[4] = b1.x; bin[5] = b1.y; bin[6] = b1.z; bin[7] = b1.w;
  }

  float Wo[3][8];
#pragma unroll
  for (int o = 0; o < 3; ++o) {
    float4 w0 = ((const float4*)W_out)[o * 128 + lane];
    float4 w1 = ((const float4*)W_out)[o * 128 + 64 + lane];
    Wo[o][0] = w0.x; Wo[o][1] = w0.y; Wo[o][2] = w0.z; Wo[o][3] = w0.w;
    Wo[o][4] = w1.x; Wo[o][5] = w1.y; Wo[o][6] = w1.z; Wo[o][7] = w1.w;
  }
  const float bo0 = b_out[0], bo1 = b_out[1], bo2 = b_out[2];

  // ---- initial p = V @ h0 ----
  float hv[8];
  {
    const float4* h4 = (const float4*)(hidden + (size_t)b * NH);
    float4 h0 = h4[lane];
    float4 h1 = h4[64 + lane];
    hv[0] = h0.x; hv[1] = h0.y; hv[2] = h0.z; hv[3] = h0.w;
    hv[4] = h1.x; hv[5] = h1.y; hv[6] = h1.z; hv[7] = h1.w;
  }
  float p0, p1, p2, p3;
  {
    float s0 = 0.f, s1 = 0.f, s2 = 0.f, s3 = 0.f;
#pragma unroll
    for (int j = 0; j < 8; ++j) {
      s0 = fmaf(hv[j], Vv[0][j], s0);
      s1 = fmaf(hv[j], Vv[1][j], s1);
      s2 = fmaf(hv[j], Vv[2][j], s2);
      s3 = fmaf(hv[j], Vv[3][j], s3);
    }
    p0 = bcast_lane63(wave_sum63(s0));
    p1 = bcast_lane63(wave_sum63(s1));
    p2 = bcast_lane63(wave_sum63(s2));
    p3 = bcast_lane63(wave_sum63(s3));
  }

  __syncthreads();  // xs ready

  float cx0 = xs[0], cx1 = xs[1], cx2 = xs[2];

  float* rbase = out_r + (size_t)b * NT * NH;
  float* ybase = out_y + (size_t)b * NT * NO;

  for (int t = 0; t < NT; ++t) {
    // a_j = W_in x_t + b_in + U^T p
    float a[8];
#pragma unroll
    for (int j = 0; j < 8; ++j) {
      float v = bin[j];
      v = fmaf(cx0, Wi[j][0], v);
      v = fmaf(cx1, Wi[j][1], v);
      v = fmaf(cx2, Wi[j][2], v);
      v = fmaf(p0, Uv[0][j], v);
      v = fmaf(p1, Uv[1][j], v);
      v = fmaf(p2, Uv[2][j], v);
      v = fmaf(p3, Uv[3][j], v);
      a[j] = v;
    }
    // prefetch next step's x while tanh/reduce run
    if (t + 1 < NT) {
      cx0 = xs[(t + 1) * 3 + 0];
      cx1 = xs[(t + 1) * 3 + 1];
      cx2 = xs[(t + 1) * 3 + 2];
    }

#pragma unroll
    for (int j = 0; j < 8; ++j) hv[j] = fast_tanh(a[j]);

    // store r_out[b][t][:] — two coalesced dwordx4
    float4* rp = (float4*)(rbase + (size_t)t * NH);
    rp[lane] = make_float4(hv[0], hv[1], hv[2], hv[3]);
    rp[64 + lane] = make_float4(hv[4], hv[5], hv[6], hv[7]);

    // partials: p' = V h ; q = W_out h
    float s0 = 0.f, s1 = 0.f, s2 = 0.f, s3 = 0.f;
    float q0 = 0.f, q1 = 0.f, q2 = 0.f;
#pragma unroll
    for (int j = 0; j < 8; ++j) {
      s0 = fmaf(hv[j], Vv[0][j], s0);
      s1 = fmaf(hv[j], Vv[1][j], s1);
      s2 = fmaf(hv[j], Vv[2][j], s2);
      s3 = fmaf(hv[j], Vv[3][j], s3);
      q0 = fmaf(hv[j], Wo[0][j], q0);
      q1 = fmaf(hv[j], Wo[1][j], q1);
      q2 = fmaf(hv[j], Wo[2][j], q2);
    }
    s0 = wave_sum63(s0);
    s1 = wave_sum63(s1);
    s2 = wave_sum63(s2);
    s3 = wave_sum63(s3);
    q0 = wave_sum63(q0);
    q1 = wave_sum63(q1);
    q2 = wave_sum63(q2);
    p0 = bcast_lane63(s0);
    p1 = bcast_lane63(s1);
    p2 = bcast_lane63(s2);
    p3 = bcast_lane63(s3);
    if (lane == 63) {
      float* yp = ybase + t * NO;
      yp[0] = q0 + bo0;
      yp[1] = q1 + bo1;
      yp[2] = q2 + bo2;
    }
  }

  // h_last = h_{T-1}
  float4* hp = (float4*)(out_h + (size_t)b * NH);
  hp[lane] = make_float4(hv[0], hv[1], hv[2], hv[3]);
  hp[64 + lane] = make_float4(hv[4], hv[5], hv[6], hv[7]);
}

extern "C" void kernel_launch(void* const* d_in, const int* in_sizes, int n_in,
                              void* d_out, int out_size, void* d_ws, size_t ws_size,
                              hipStream_t stream) {
  const float* x      = (const float*)d_in[0];
  const float* hidden = (const float*)d_in[1];
  const float* U      = (const float*)d_in[2];
  const float* V      = (const float*)d_in[3];
  const float* W_in   = (const float*)d_in[4];
  const float* b_in   = (const float*)d_in[5];
  const float* W_out  = (const float*)d_in[6];
  const float* b_out  = (const float*)d_in[7];

  float* out = (float*)d_out;
  float* out_y = out;                                  // [B,T,3]
  float* out_h = out + (size_t)NB * NT * NO;           // [B,512]
  float* out_r = out_h + (size_t)NB * NH;              // [B,T,512]

  hipLaunchKernelGGL(lowrank_rnn_kernel, dim3(NB), dim3(64), 0, stream,
                     x, hidden, U, V, W_in, b_in, W_out, b_out,
                     out_y, out_h, out_r);
}